// Round 17
// baseline (257.242 us; speedup 1.0000x reference)
//
#include <hip/hip_runtime.h>

// GraphNet forward on MI355X — Round 14: G2 with m201-faithful per-phase
// stage interleave. r13 failed because all 8 gl_lds were clustered at tile
// tail (m196's measured hurt-variant, -7..-27%). This round distributes them:
// BK=32, 4 bufs (stage target buf[(t+3)&3]=buf[(t-1)&3] is dead => race-free).
// Per tile t: P0 {rd A-mh0(4)+B(4) | stage-A(t+3) 2 gl_lds | bar | lgkm0+SB0 |
//                 setprio 16 MFMA | bar}
//             P1 {rd A-mh1(4)      | stage-B(t+3) 2 gl_lds | bar | lgkm0+SB0 |
//                 setprio 16 MFMA | vmcnt(8/4/0 counted) | bar}
// Ledger: prologue stages 0,1,2 (12 out) -> vmcnt(8)=tile0 landed. Steady:
// outstanding {t+1,t+2,t+3}=12 -> vmcnt(8) lands t+1 (FIFO). Tail: NT-3 ->
// vmcnt(4), NT-2 -> vmcnt(0), NT-1 skip. Swizzle/epilogue = r9 (validated).
// Rest of pipeline validated rounds 6-13. Output f32; ws 70.5MB.
typedef unsigned short u16;
typedef unsigned int u32;
typedef unsigned long long u64;
typedef __bf16 bf16x8 __attribute__((ext_vector_type(8)));
typedef float f32x4 __attribute__((ext_vector_type(4)));

static __device__ __forceinline__ float bf2f(u16 u) {
  return __uint_as_float(((u32)u) << 16);
}
static __device__ __forceinline__ u16 f2bf(float f) {
  u32 x = __float_as_uint(f);
  return (u16)((x + 0x7fffu + ((x >> 16) & 1u)) >> 16);  // RNE
}
static __device__ __forceinline__ void gl_lds16(const u16* g, u16* l) {
  __builtin_amdgcn_global_load_lds(
      (const __attribute__((address_space(1))) void*)g,
      (__attribute__((address_space(3))) void*)l, 16, 0, 0);
}
static __device__ __forceinline__ u64 pack4bf(f32x4 v) {
  u64 r = (u64)f2bf(v[0]);
  r |= (u64)f2bf(v[1]) << 16;
  r |= (u64)f2bf(v[2]) << 32;
  r |= (u64)f2bf(v[3]) << 48;
  return r;
}

// ---------- transpose f32[K][N] -> bf16[N][Kpad] (validated r10) ----------
__global__ __launch_bounds__(256) void k_transpose(const float* __restrict__ in,
                                                   u16* __restrict__ out,
                                                   int K, int N, int Kpad) {
  __shared__ u16 t[64 * 68];
  const int tid = threadIdx.x;
  const int k0 = blockIdx.x * 64, n0 = blockIdx.y * 64;
#pragma unroll
  for (int pass = 0; pass < 4; pass++) {
    int ki = pass * 16 + (tid >> 4);
    int nj = (tid & 15) * 4;
    f32x4 v = {0.f, 0.f, 0.f, 0.f};
    if (k0 + ki < K) v = *(const f32x4*)&in[(long)(k0 + ki) * N + n0 + nj];
    *(u64*)&t[ki * 68 + nj] = pack4bf(v);
  }
  __syncthreads();
#pragma unroll
  for (int pass = 0; pass < 4; pass++) {
    int ni = pass * 16 + (tid >> 4);
    int kj = (tid & 15) * 4;
    if (k0 + kj < Kpad) {
      u64 w = (u64)t[(kj + 0) * 68 + ni] | ((u64)t[(kj + 1) * 68 + ni] << 16) |
              ((u64)t[(kj + 2) * 68 + ni] << 32) | ((u64)t[(kj + 3) * 68 + ni] << 48);
      *(u64*)&out[(long)(n0 + ni) * Kpad + k0 + kj] = w;
    }
  }
}

// ---------- e_in builder: [4096][160] bf16 ----------
__global__ __launch_bounds__(192) void k_build_ein(const float* __restrict__ edges,
                                                   const float* __restrict__ nodes,
                                                   const float* __restrict__ g,
                                                   const int* __restrict__ senders,
                                                   const int* __restrict__ receivers,
                                                   u16* __restrict__ ein) {
  const int e = blockIdx.x;
  const int x = threadIdx.x;
  if (x >= 160) return;
  const int s = senders[e], r = receivers[e];
  float v;
  if (x < 16) v = edges[(long)e * 16 + x];
  else if (x < 80) v = nodes[(long)s * 64 + (x - 16)];
  else if (x < 144) v = nodes[(long)r * 64 + (x - 80)];
  else if (x < 152) v = g[x - 144];
  else v = 0.f;
  ein[(long)e * 160 + x] = f2bf(v);
}

// ---------- 128^2 MFMA GEMM (G1, validated) ----------
template <int MODE>
__global__ __launch_bounds__(256) void k_mgemm(const u16* __restrict__ A,
                                               const u16* __restrict__ BT,
                                               const float* __restrict__ bias,
                                               void* __restrict__ C, int M, int N, int K) {
  __shared__ alignas(16) u16 As[128 * 32];
  __shared__ alignas(16) u16 Bs[128 * 32];
  const int tid = threadIdx.x;
  const int lane = tid & 63, wid = tid >> 6;
  const int wr = wid >> 1, wc = wid & 1;
  const int m0 = blockIdx.x * 128, n0 = blockIdx.y * 128;
  const int lr = lane & 15, lk = lane >> 4;
  const int swz = (lk ^ ((lr >> 1) & 3)) << 3;
  const int srow = tid >> 2;
  const int skk = ((tid & 3) ^ ((tid >> 3) & 3)) << 3;

  f32x4 acc[4][4];
#pragma unroll
  for (int i = 0; i < 4; i++)
#pragma unroll
    for (int j = 0; j < 4; j++) acc[i][j] = {0.f, 0.f, 0.f, 0.f};

  for (int kt = 0; kt < K; kt += 32) {
#pragma unroll
    for (int rep = 0; rep < 2; rep++) {
      int row = rep * 64 + srow;
      int o = rep * 2048 + tid * 8;
      gl_lds16(&A[(long)(m0 + row) * K + kt + skk], &As[o]);
      gl_lds16(&BT[(long)(n0 + row) * K + kt + skk], &Bs[o]);
    }
    __syncthreads();
    bf16x8 af[4], bfr[4];
#pragma unroll
    for (int mi = 0; mi < 4; mi++)
      af[mi] = *(const bf16x8*)&As[(wr * 64 + mi * 16 + lr) * 32 + swz];
#pragma unroll
    for (int ni = 0; ni < 4; ni++)
      bfr[ni] = *(const bf16x8*)&Bs[(wc * 64 + ni * 16 + lr) * 32 + swz];
#pragma unroll
    for (int mi = 0; mi < 4; mi++)
#pragma unroll
      for (int ni = 0; ni < 4; ni++)
        acc[mi][ni] =
            __builtin_amdgcn_mfma_f32_16x16x32_bf16(af[mi], bfr[ni], acc[mi][ni], 0, 0, 0);
    __syncthreads();
  }
#pragma unroll
  for (int ni = 0; ni < 4; ni++) {
    int col = n0 + wc * 64 + ni * 16 + lr;
    float bb = bias[col];
#pragma unroll
    for (int mi = 0; mi < 4; mi++) {
      int row = m0 + wr * 64 + mi * 16 + lk * 4;
#pragma unroll
      for (int r = 0; r < 4; r++) {
        float v = fmaxf(acc[mi][ni][r] + bb, 0.f);
        if (MODE == 0) ((u16*)C)[(long)(row + r) * N + col] = f2bf(v);
        else ((float*)C)[(long)(row + r) * N + col] = v;
      }
    }
  }
}

// ---------- 256^2 G2: BK=32, 4-buf, 2 phases/tile, per-phase stage interleave --
__global__ __launch_bounds__(512, 1) void k_gemm256(const u16* __restrict__ A,
                                                    const u16* __restrict__ BT,
                                                    const float* __restrict__ bias,
                                                    float* __restrict__ C, int N, int K) {
  __shared__ alignas(16) u16 lds[65536];  // 4 bufs x (A 16KB + B 16KB)
  const int tid = threadIdx.x;
  const int lane = tid & 63, wid = tid >> 6;
  const int wr = wid >> 2, wc = wid & 3;
  const int orig = blockIdx.x;
  const int xc = orig & 7, jj = orig >> 3;
  const int m0 = (2 * xc + (jj >> 4)) * 256;
  const int n0 = (jj & 15) * 256;
  const int lr = lane & 15, lk = lane >> 4;
  const int swz = (lk ^ ((lr >> 1) & 3)) << 3;
  const int NT = K >> 5;  // 128

  const int srow = wid * 16 + (lane >> 2);
  const int sq = ((lane & 3) ^ ((lane >> 3) & 3)) << 3;
  const int sdst = wid * 512 + lane * 8;

  f32x4 acc[8][4];
#pragma unroll
  for (int i = 0; i < 8; i++)
#pragma unroll
    for (int j = 0; j < 4; j++) acc[i][j] = {0.f, 0.f, 0.f, 0.f};

#define STAGE_A(T)                                                         \
  {                                                                        \
    const int kt_ = (T) * 32;                                              \
    u16* Ab_ = &lds[((T) & 3) * 16384];                                    \
    gl_lds16(&A[(long)(m0 + srow) * K + kt_ + sq], Ab_ + sdst);            \
    gl_lds16(&A[(long)(m0 + 128 + srow) * K + kt_ + sq], Ab_ + 4096 + sdst);\
  }
#define STAGE_B(T)                                                         \
  {                                                                        \
    const int kt_ = (T) * 32;                                              \
    u16* Bb_ = &lds[((T) & 3) * 16384] + 8192;                             \
    gl_lds16(&BT[(long)(n0 + srow) * K + kt_ + sq], Bb_ + sdst);           \
    gl_lds16(&BT[(long)(n0 + 128 + srow) * K + kt_ + sq], Bb_ + 4096 + sdst);\
  }

  // prologue: tiles 0,1,2 staged (12 out); certify tile 0; publish
  STAGE_A(0) STAGE_B(0)
  STAGE_A(1) STAGE_B(1)
  STAGE_A(2) STAGE_B(2)
  asm volatile("s_waitcnt vmcnt(8)" ::: "memory");
  __builtin_amdgcn_s_barrier();

  for (int t = 0; t < NT; t++) {
    const u16* Ab = &lds[(t & 3) * 16384];
    const u16* Bb = Ab + 8192;
    bf16x8 afA[4], afB[4], bf[4];
    // ---- P0: quadrant mh0 ----
#pragma unroll
    for (int mi = 0; mi < 4; mi++)
      afA[mi] = *(const bf16x8*)&Ab[(wr * 128 + mi * 16 + lr) * 32 + swz];
#pragma unroll
    for (int ni = 0; ni < 4; ni++)
      bf[ni] = *(const bf16x8*)&Bb[(wc * 64 + ni * 16 + lr) * 32 + swz];
    if (t + 3 < NT) STAGE_A(t + 3)
    __builtin_amdgcn_s_barrier();
    asm volatile("s_waitcnt lgkmcnt(0)" ::: "memory");
    __builtin_amdgcn_sched_barrier(0);
    __builtin_amdgcn_s_setprio(1);
#pragma unroll
    for (int mi = 0; mi < 4; mi++)
#pragma unroll
      for (int ni = 0; ni < 4; ni++)
        acc[mi][ni] =
            __builtin_amdgcn_mfma_f32_16x16x32_bf16(afA[mi], bf[ni], acc[mi][ni], 0, 0, 0);
    __builtin_amdgcn_s_setprio(0);
    __builtin_amdgcn_s_barrier();
    // ---- P1: quadrant mh1 (reuse bf) ----
#pragma unroll
    for (int mi = 0; mi < 4; mi++)
      afB[mi] = *(const bf16x8*)&Ab[(wr * 128 + 64 + mi * 16 + lr) * 32 + swz];
    if (t + 3 < NT) STAGE_B(t + 3)
    __builtin_amdgcn_s_barrier();
    asm volatile("s_waitcnt lgkmcnt(0)" ::: "memory");
    __builtin_amdgcn_sched_barrier(0);
    __builtin_amdgcn_s_setprio(1);
#pragma unroll
    for (int mi = 0; mi < 4; mi++)
#pragma unroll
      for (int ni = 0; ni < 4; ni++)
        acc[4 + mi][ni] =
            __builtin_amdgcn_mfma_f32_16x16x32_bf16(afB[mi], bf[ni], acc[4 + mi][ni], 0, 0, 0);
    __builtin_amdgcn_s_setprio(0);
    // counted vmcnt: certify tile t+1 before its reads (FIFO: t+1 oldest)
    if (t < NT - 3) {
      asm volatile("s_waitcnt vmcnt(8)" ::: "memory");
    } else if (t == NT - 3) {
      asm volatile("s_waitcnt vmcnt(4)" ::: "memory");
    } else if (t == NT - 2) {
      asm volatile("s_waitcnt vmcnt(0)" ::: "memory");
    }
    __builtin_amdgcn_s_barrier();
  }
#undef STAGE_B
#undef STAGE_A

#pragma unroll
  for (int ni = 0; ni < 4; ni++) {
    int col = n0 + wc * 64 + ni * 16 + lr;
    float bb = bias[col];
#pragma unroll
    for (int mi = 0; mi < 8; mi++) {
      int row = m0 + wr * 128 + mi * 16 + lk * 4;
#pragma unroll
      for (int r = 0; r < 4; r++)
        C[(long)(row + r) * N + col] = fmaxf(acc[mi][ni][r] + bb, 0.f);
    }
  }
}

// ---------- MFMA scatter-GEMM (validated) ----------
__global__ __launch_bounds__(256) void k_scatter_m(const float* __restrict__ E,
                                                   const u16* __restrict__ BT,
                                                   const int* __restrict__ senders,
                                                   const int* __restrict__ receivers,
                                                   float* __restrict__ accb) {
  const int K = 4096;
  __shared__ alignas(16) u16 As[128 * 32];
  __shared__ alignas(16) u16 Bs[128 * 32];
  const int tid = threadIdx.x;
  const int lane = tid & 63, wid = tid >> 6;
  const int wr = wid >> 1, wc = wid & 1;
  const int m0 = blockIdx.x * 128;
  const int kbase = blockIdx.y * 512;
  const int lr = lane & 15, lk = lane >> 4;
  const int swz = (lk ^ ((lr >> 1) & 3)) << 3;
  const int srow = tid >> 2;
  const int skk = ((tid & 3) ^ ((tid >> 3) & 3)) << 3;

  f32x4 acc[4][4];
#pragma unroll
  for (int i = 0; i < 4; i++)
#pragma unroll
    for (int j = 0; j < 4; j++) acc[i][j] = {0.f, 0.f, 0.f, 0.f};

  for (int kt = kbase; kt < kbase + 512; kt += 32) {
#pragma unroll
    for (int p = 0; p < 4; p++) {
      int idx = p * 256 + tid;
      int r = idx >> 3;
      int kq = idx & 7;
      f32x4 v = *(const f32x4*)&E[(long)(m0 + r) * 4096 + kt + kq * 4];
      int gq = (kq >> 1) ^ ((r >> 1) & 3);
      *(u64*)&As[r * 32 + gq * 8 + (kq & 1) * 4] = pack4bf(v);
    }
#pragma unroll
    for (int rep = 0; rep < 2; rep++) {
      int row = rep * 64 + srow;
      gl_lds16(&BT[(long)row * K + kt + skk], &Bs[rep * 2048 + tid * 8]);
    }
    __syncthreads();
    bf16x8 af[4], bfr[4];
#pragma unroll
    for (int mi = 0; mi < 4; mi++)
      af[mi] = *(const bf16x8*)&As[(wr * 64 + mi * 16 + lr) * 32 + swz];
#pragma unroll
    for (int ni = 0; ni < 4; ni++)
      bfr[ni] = *(const bf16x8*)&Bs[(wc * 64 + ni * 16 + lr) * 32 + swz];
#pragma unroll
    for (int mi = 0; mi < 4; mi++)
#pragma unroll
      for (int ni = 0; ni < 4; ni++)
        acc[mi][ni] =
            __builtin_amdgcn_mfma_f32_16x16x32_bf16(af[mi], bfr[ni], acc[mi][ni], 0, 0, 0);
    __syncthreads();
  }
#pragma unroll
  for (int mi = 0; mi < 4; mi++) {
#pragma unroll
    for (int r = 0; r < 4; r++) {
      int e = m0 + wr * 64 + mi * 16 + lk * 4 + r;
#pragma unroll
      for (int ni = 0; ni < 4; ni++) {
        int col = wc * 64 + ni * 16 + lr;
        int tgt = (col < 64) ? senders[e] : receivers[e];
        atomicAdd(&accb[(long)tgt * 64 + (col & 63)], acc[mi][ni][r]);
      }
    }
  }
}

// ---------- final node MLP, pure f32 (validated) ----------
__global__ __launch_bounds__(256) void k_final(const float* __restrict__ nodes,
                                               const float* __restrict__ g,
                                               const float* __restrict__ nW1,
                                               const float* __restrict__ nb1,
                                               const float* __restrict__ nW2,
                                               const float* __restrict__ nb2,
                                               const float* __restrict__ zpre,
                                               float* __restrict__ out0) {
  __shared__ float h2[64 * 64];
  __shared__ float gb[64];
  const int tid = threadIdx.x;
  const long n0 = (long)blockIdx.x * 64;
  if (tid < 64) {
    float s = nb1[tid];
#pragma unroll
    for (int j = 0; j < 8; j++) s += g[j] * nW1[(long)(8256 + j) * 64 + tid];
    gb[tid] = s;
  }
  __syncthreads();
#pragma unroll 2
  for (int rep = 0; rep < 16; rep++) {
    int idx = rep * 256 + tid;
    int i = idx >> 6, c = idx & 63;
    float z = gb[c] + zpre[(n0 + i) * 64 + c];
    const float* nr = nodes + (n0 + i) * 64;
#pragma unroll 8
    for (int k = 0; k < 64; k++) z += nr[k] * nW1[(long)k * 64 + c];
    h2[idx] = fmaxf(z, 0.f);
  }
  __syncthreads();
#pragma unroll 2
  for (int rep = 0; rep < 16; rep++) {
    int idx = rep * 256 + tid;
    int i = idx >> 6, c = idx & 63;
    float z = nb2[c];
#pragma unroll 8
    for (int k = 0; k < 64; k++) z += h2[i * 64 + k] * nW2[(long)k * 64 + c];
    out0[(n0 + i) * 64 + c] = fmaxf(z, 0.f);
  }
}

extern "C" void kernel_launch(void* const* d_in, const int* in_sizes, int n_in,
                              void* d_out, int out_size, void* d_ws, size_t ws_size,
                              hipStream_t stream) {
  const float* nodes = (const float*)d_in[0];
  const float* edges = (const float*)d_in[1];
  const float* g = (const float*)d_in[2];
  const int* senders = (const int*)d_in[3];
  const int* receivers = (const int*)d_in[4];
  const float* eW1 = (const float*)d_in[5];
  const float* eb1 = (const float*)d_in[6];
  const float* eW2 = (const float*)d_in[7];
  const float* eb2 = (const float*)d_in[8];
  const float* nW1 = (const float*)d_in[9];
  const float* nb1 = (const float*)d_in[10];
  const float* nW2 = (const float*)d_in[11];
  const float* nb2 = (const float*)d_in[12];

  char* ws = (char*)d_ws;
  u16* eW1T = (u16*)(ws + 0);        // [4096][160] bf16, dies after G1
  float* accb = (float*)(ws + 0);    // [8192][64] f32, live after memset (post-G1)
  u16* ein = (u16*)(ws + 2097152);   // [4096][160] bf16, dies after G1
  u16* nWmT = (u16*)(ws + 2097152);  // [128][4096] bf16, written after G1
  u16* eW2T = (u16*)(ws + 3407872);  // [4096][4096] bf16
  u16* h = (u16*)(ws + 36962304);    // [4096][4096] bf16 (ends 70.5MB)

  float* out_nodes = (float*)d_out;
  float* out_edges = (float*)d_out + 524288;

  dim3 b256(256);
  k_transpose<<<dim3(3, 64), b256, 0, stream>>>(eW1, eW1T, 152, 4096, 160);
  k_transpose<<<dim3(64, 64), b256, 0, stream>>>(eW2, eW2T, 4096, 4096, 4096);
  k_build_ein<<<4096, 192, 0, stream>>>(edges, nodes, g, senders, receivers, ein);

  k_mgemm<0><<<dim3(32, 32), b256, 0, stream>>>(ein, eW1T, eb1, h, 4096, 4096, 160);

  // ein/eW1T dead: build nWmT + clear accb before scatter.
  k_transpose<<<dim3(64, 1), b256, 0, stream>>>(nW1 + 64 * 64, nWmT, 4096, 64, 4096);
  k_transpose<<<dim3(64, 1), b256, 0, stream>>>(nW1 + 4160 * 64, nWmT + (long)64 * 4096,
                                                4096, 64, 4096);
  hipMemsetAsync(accb, 0, 8192 * 64 * 4, stream);

  k_gemm256<<<dim3(256), dim3(512), 0, stream>>>(h, eW2T, eb2, out_edges, 4096, 4096);

  k_scatter_m<<<dim3(32, 8), b256, 0, stream>>>(out_edges, nWmT, senders, receivers, accb);
  k_final<<<128, b256, 0, stream>>>(nodes, g, nW1, nb1, nW2, nb2, accb, out_nodes);
}

// Round 18
// 229.999 us; speedup vs baseline: 1.1184x; 1.1184x over previous
//
#include <hip/hip_runtime.h>

// GraphNet forward on MI355X — Round 18: G2 reverted to best-measured body
// (r9/r11: BK=32, 4-buf, counted vmcnt(8), 1 barrier/tile, XCD 1D grid,
// conflict-free swizzle — 135-136us, 4 schedule variants failed to beat it).
// This round: tail. (a) k_final stages nW1/nW2/nodes in LDS f32 (was ~2048
// global loads/thread, latency-bound); bitwise-identical math. (b) 10->7
// launches: k_prep = {eW1T transpose + build_ein}, k_mid = {2x nWmT transpose
// + accb zero}. Ordering: nWmT overlays ein, accb overlays eW1T => k_mid
// stays post-G1. Output f32; ws 70.5MB (validated r7-r17).
typedef unsigned short u16;
typedef unsigned int u32;
typedef unsigned long long u64;
typedef __bf16 bf16x8 __attribute__((ext_vector_type(8)));
typedef float f32x4 __attribute__((ext_vector_type(4)));

static __device__ __forceinline__ float bf2f(u16 u) {
  return __uint_as_float(((u32)u) << 16);
}
static __device__ __forceinline__ u16 f2bf(float f) {
  u32 x = __float_as_uint(f);
  return (u16)((x + 0x7fffu + ((x >> 16) & 1u)) >> 16);  // RNE
}
static __device__ __forceinline__ void gl_lds16(const u16* g, u16* l) {
  __builtin_amdgcn_global_load_lds(
      (const __attribute__((address_space(1))) void*)g,
      (__attribute__((address_space(3))) void*)l, 16, 0, 0);
}
static __device__ __forceinline__ u64 pack4bf(f32x4 v) {
  u64 r = (u64)f2bf(v[0]);
  r |= (u64)f2bf(v[1]) << 16;
  r |= (u64)f2bf(v[2]) << 32;
  r |= (u64)f2bf(v[3]) << 48;
  return r;
}

// transpose body: f32[K][N] tile at (k0,n0) -> bf16[N][Kpad] (validated r10)
static __device__ __forceinline__ void transpose_tile(const float* in, u16* out,
                                                      int K, int N, int Kpad,
                                                      int k0, int n0, int tid,
                                                      u16* t /*64*68*/) {
#pragma unroll
  for (int pass = 0; pass < 4; pass++) {
    int ki = pass * 16 + (tid >> 4);
    int nj = (tid & 15) * 4;
    f32x4 v = {0.f, 0.f, 0.f, 0.f};
    if (k0 + ki < K) v = *(const f32x4*)&in[(long)(k0 + ki) * N + n0 + nj];
    *(u64*)&t[ki * 68 + nj] = pack4bf(v);
  }
  __syncthreads();
#pragma unroll
  for (int pass = 0; pass < 4; pass++) {
    int ni = pass * 16 + (tid >> 4);
    int kj = (tid & 15) * 4;
    if (k0 + kj < Kpad) {
      u64 w = (u64)t[(kj + 0) * 68 + ni] | ((u64)t[(kj + 1) * 68 + ni] << 16) |
              ((u64)t[(kj + 2) * 68 + ni] << 32) | ((u64)t[(kj + 3) * 68 + ni] << 48);
      *(u64*)&out[(long)(n0 + ni) * Kpad + k0 + kj] = w;
    }
  }
}

// ---------- k_prep: blocks [0,192) eW1T transpose; [192,2752) build_ein ----------
__global__ __launch_bounds__(256) void k_prep(const float* __restrict__ eW1,
                                              u16* __restrict__ eW1T,
                                              const float* __restrict__ edges,
                                              const float* __restrict__ nodes,
                                              const float* __restrict__ g,
                                              const int* __restrict__ senders,
                                              const int* __restrict__ receivers,
                                              u16* __restrict__ ein) {
  __shared__ u16 t[64 * 68];
  const int b = blockIdx.x;
  const int tid = threadIdx.x;
  if (b < 192) {
    transpose_tile(eW1, eW1T, 152, 4096, 160, (b % 3) * 64, (b / 3) * 64, tid, t);
    return;
  }
  int idx = (b - 192) * 256 + tid;  // [0, 655360)
  int e = idx / 160, x = idx - e * 160;
  float v;
  if (x < 16) v = edges[(long)e * 16 + x];
  else if (x < 80) v = nodes[(long)senders[e] * 64 + (x - 16)];
  else if (x < 144) v = nodes[(long)receivers[e] * 64 + (x - 80)];
  else if (x < 152) v = g[x - 144];
  else v = 0.f;
  ein[idx] = f2bf(v);
}

// ---------- standalone transpose (eW2T) ----------
__global__ __launch_bounds__(256) void k_transpose(const float* __restrict__ in,
                                                   u16* __restrict__ out,
                                                   int K, int N, int Kpad) {
  __shared__ u16 t[64 * 68];
  transpose_tile(in, out, K, N, Kpad, blockIdx.x * 64, blockIdx.y * 64,
                 threadIdx.x, t);
}

// ---------- k_mid: [0,64) nWmT half0; [64,128) half1; [128,192) zero accb ----------
__global__ __launch_bounds__(256) void k_mid(const float* __restrict__ nW1,
                                             u16* __restrict__ nWmT,
                                             float* __restrict__ accb) {
  __shared__ u16 t[64 * 68];
  const int b = blockIdx.x;
  const int tid = threadIdx.x;
  if (b < 64) {
    transpose_tile(nW1 + 64 * 64, nWmT, 4096, 64, 4096, b * 64, 0, tid, t);
  } else if (b < 128) {
    transpose_tile(nW1 + 4160 * 64, nWmT + (long)64 * 4096, 4096, 64, 4096,
                   (b - 64) * 64, 0, tid, t);
  } else {
    f32x4* a4 = (f32x4*)accb;
    long base = ((long)(b - 128) * 256 + tid) * 8;  // 16384 threads x 8 f32x4
#pragma unroll
    for (int j = 0; j < 8; j++) a4[base + j] = {0.f, 0.f, 0.f, 0.f};
  }
}

// ---------- 128^2 MFMA GEMM (G1, validated) ----------
template <int MODE>
__global__ __launch_bounds__(256) void k_mgemm(const u16* __restrict__ A,
                                               const u16* __restrict__ BT,
                                               const float* __restrict__ bias,
                                               void* __restrict__ C, int M, int N, int K) {
  __shared__ alignas(16) u16 As[128 * 32];
  __shared__ alignas(16) u16 Bs[128 * 32];
  const int tid = threadIdx.x;
  const int lane = tid & 63, wid = tid >> 6;
  const int wr = wid >> 1, wc = wid & 1;
  const int m0 = blockIdx.x * 128, n0 = blockIdx.y * 128;
  const int lr = lane & 15, lk = lane >> 4;
  const int swz = (lk ^ ((lr >> 1) & 3)) << 3;
  const int srow = tid >> 2;
  const int skk = ((tid & 3) ^ ((tid >> 3) & 3)) << 3;

  f32x4 acc[4][4];
#pragma unroll
  for (int i = 0; i < 4; i++)
#pragma unroll
    for (int j = 0; j < 4; j++) acc[i][j] = {0.f, 0.f, 0.f, 0.f};

  for (int kt = 0; kt < K; kt += 32) {
#pragma unroll
    for (int rep = 0; rep < 2; rep++) {
      int row = rep * 64 + srow;
      int o = rep * 2048 + tid * 8;
      gl_lds16(&A[(long)(m0 + row) * K + kt + skk], &As[o]);
      gl_lds16(&BT[(long)(n0 + row) * K + kt + skk], &Bs[o]);
    }
    __syncthreads();
    bf16x8 af[4], bfr[4];
#pragma unroll
    for (int mi = 0; mi < 4; mi++)
      af[mi] = *(const bf16x8*)&As[(wr * 64 + mi * 16 + lr) * 32 + swz];
#pragma unroll
    for (int ni = 0; ni < 4; ni++)
      bfr[ni] = *(const bf16x8*)&Bs[(wc * 64 + ni * 16 + lr) * 32 + swz];
#pragma unroll
    for (int mi = 0; mi < 4; mi++)
#pragma unroll
      for (int ni = 0; ni < 4; ni++)
        acc[mi][ni] =
            __builtin_amdgcn_mfma_f32_16x16x32_bf16(af[mi], bfr[ni], acc[mi][ni], 0, 0, 0);
    __syncthreads();
  }
#pragma unroll
  for (int ni = 0; ni < 4; ni++) {
    int col = n0 + wc * 64 + ni * 16 + lr;
    float bb = bias[col];
#pragma unroll
    for (int mi = 0; mi < 4; mi++) {
      int row = m0 + wr * 64 + mi * 16 + lk * 4;
#pragma unroll
      for (int r = 0; r < 4; r++) {
        float v = fmaxf(acc[mi][ni][r] + bb, 0.f);
        if (MODE == 0) ((u16*)C)[(long)(row + r) * N + col] = f2bf(v);
        else ((float*)C)[(long)(row + r) * N + col] = v;
      }
    }
  }
}

// ---------- 256^2 G2: r9/r11 validated schedule + XCD 1D grid ----------
__global__ __launch_bounds__(512, 1) void k_gemm256(const u16* __restrict__ A,
                                                    const u16* __restrict__ BT,
                                                    const float* __restrict__ bias,
                                                    float* __restrict__ C, int N, int K) {
  __shared__ alignas(16) u16 lds[65536];  // 128 KB
  const int tid = threadIdx.x;
  const int lane = tid & 63, wid = tid >> 6;
  const int wr = wid >> 2, wc = wid & 3;
  const int orig = blockIdx.x;
  const int xc = orig & 7, jj = orig >> 3;
  const int m0 = (2 * xc + (jj >> 4)) * 256;
  const int n0 = (jj & 15) * 256;
  const int lr = lane & 15, lk = lane >> 4;
  const int swz = (lk ^ ((lr >> 1) & 3)) << 3;
  const int NT = K >> 5;

  const int srow = wid * 16 + (lane >> 2);
  const int sq = ((lane & 3) ^ ((lane >> 3) & 3)) << 3;
  const int sdst = wid * 512 + lane * 8;

  f32x4 acc[8][4];
#pragma unroll
  for (int i = 0; i < 8; i++)
#pragma unroll
    for (int j = 0; j < 4; j++) acc[i][j] = {0.f, 0.f, 0.f, 0.f};

#define STAGE_TILE(T)                                                              \
  {                                                                                \
    const int kt_ = (T) * 32;                                                      \
    u16* Ab_ = &lds[((T) & 3) * 16384];                                            \
    u16* Bb_ = Ab_ + 8192;                                                         \
    gl_lds16(&A[(long)(m0 + srow) * K + kt_ + sq], Ab_ + sdst);                    \
    gl_lds16(&A[(long)(m0 + 128 + srow) * K + kt_ + sq], Ab_ + 4096 + sdst);       \
    gl_lds16(&BT[(long)(n0 + srow) * K + kt_ + sq], Bb_ + sdst);                   \
    gl_lds16(&BT[(long)(n0 + 128 + srow) * K + kt_ + sq], Bb_ + 4096 + sdst);      \
  }

  STAGE_TILE(0)
  STAGE_TILE(1)
  STAGE_TILE(2)

  for (int t = 0; t < NT; t++) {
    if (t < NT - 2) {
      asm volatile("s_waitcnt vmcnt(8)" ::: "memory");
    } else if (t == NT - 2) {
      asm volatile("s_waitcnt vmcnt(4)" ::: "memory");
    } else {
      asm volatile("s_waitcnt vmcnt(0)" ::: "memory");
    }
    __builtin_amdgcn_s_barrier();
    if (t + 3 < NT) STAGE_TILE(t + 3)

    const u16* Ab = &lds[(t & 3) * 16384];
    const u16* Bb = Ab + 8192;
    bf16x8 af[8], bfr[4];
#pragma unroll
    for (int mi = 0; mi < 8; mi++)
      af[mi] = *(const bf16x8*)&Ab[(wr * 128 + mi * 16 + lr) * 32 + swz];
#pragma unroll
    for (int ni = 0; ni < 4; ni++)
      bfr[ni] = *(const bf16x8*)&Bb[(wc * 64 + ni * 16 + lr) * 32 + swz];
#pragma unroll
    for (int mi = 0; mi < 8; mi++)
#pragma unroll
      for (int ni = 0; ni < 4; ni++)
        acc[mi][ni] =
            __builtin_amdgcn_mfma_f32_16x16x32_bf16(af[mi], bfr[ni], acc[mi][ni], 0, 0, 0);
  }
#undef STAGE_TILE

#pragma unroll
  for (int ni = 0; ni < 4; ni++) {
    int col = n0 + wc * 64 + ni * 16 + lr;
    float bb = bias[col];
#pragma unroll
    for (int mi = 0; mi < 8; mi++) {
      int row = m0 + wr * 128 + mi * 16 + lk * 4;
#pragma unroll
      for (int r = 0; r < 4; r++)
        C[(long)(row + r) * N + col] = fmaxf(acc[mi][ni][r] + bb, 0.f);
    }
  }
}

// ---------- MFMA scatter-GEMM (validated) ----------
__global__ __launch_bounds__(256) void k_scatter_m(const float* __restrict__ E,
                                                   const u16* __restrict__ BT,
                                                   const int* __restrict__ senders,
                                                   const int* __restrict__ receivers,
                                                   float* __restrict__ accb) {
  const int K = 4096;
  __shared__ alignas(16) u16 As[128 * 32];
  __shared__ alignas(16) u16 Bs[128 * 32];
  const int tid = threadIdx.x;
  const int lane = tid & 63, wid = tid >> 6;
  const int wr = wid >> 1, wc = wid & 1;
  const int m0 = blockIdx.x * 128;
  const int kbase = blockIdx.y * 512;
  const int lr = lane & 15, lk = lane >> 4;
  const int swz = (lk ^ ((lr >> 1) & 3)) << 3;
  const int srow = tid >> 2;
  const int skk = ((tid & 3) ^ ((tid >> 3) & 3)) << 3;

  f32x4 acc[4][4];
#pragma unroll
  for (int i = 0; i < 4; i++)
#pragma unroll
    for (int j = 0; j < 4; j++) acc[i][j] = {0.f, 0.f, 0.f, 0.f};

  for (int kt = kbase; kt < kbase + 512; kt += 32) {
#pragma unroll
    for (int p = 0; p < 4; p++) {
      int idx = p * 256 + tid;
      int r = idx >> 3;
      int kq = idx & 7;
      f32x4 v = *(const f32x4*)&E[(long)(m0 + r) * 4096 + kt + kq * 4];
      int gq = (kq >> 1) ^ ((r >> 1) & 3);
      *(u64*)&As[r * 32 + gq * 8 + (kq & 1) * 4] = pack4bf(v);
    }
#pragma unroll
    for (int rep = 0; rep < 2; rep++) {
      int row = rep * 64 + srow;
      gl_lds16(&BT[(long)row * K + kt + skk], &Bs[rep * 2048 + tid * 8]);
    }
    __syncthreads();
    bf16x8 af[4], bfr[4];
#pragma unroll
    for (int mi = 0; mi < 4; mi++)
      af[mi] = *(const bf16x8*)&As[(wr * 64 + mi * 16 + lr) * 32 + swz];
#pragma unroll
    for (int ni = 0; ni < 4; ni++)
      bfr[ni] = *(const bf16x8*)&Bs[(wc * 64 + ni * 16 + lr) * 32 + swz];
#pragma unroll
    for (int mi = 0; mi < 4; mi++)
#pragma unroll
      for (int ni = 0; ni < 4; ni++)
        acc[mi][ni] =
            __builtin_amdgcn_mfma_f32_16x16x32_bf16(af[mi], bfr[ni], acc[mi][ni], 0, 0, 0);
    __syncthreads();
  }
#pragma unroll
  for (int mi = 0; mi < 4; mi++) {
#pragma unroll
    for (int r = 0; r < 4; r++) {
      int e = m0 + wr * 64 + mi * 16 + lk * 4 + r;
#pragma unroll
      for (int ni = 0; ni < 4; ni++) {
        int col = wc * 64 + ni * 16 + lr;
        int tgt = (col < 64) ? senders[e] : receivers[e];
        atomicAdd(&accb[(long)tgt * 64 + (col & 63)], acc[mi][ni][r]);
      }
    }
  }
}

// ---------- final node MLP: full LDS staging, pure f32 (bitwise = r6 math) ----------
__global__ __launch_bounds__(256) void k_final(const float* __restrict__ nodes,
                                               const float* __restrict__ g,
                                               const float* __restrict__ nW1,
                                               const float* __restrict__ nb1,
                                               const float* __restrict__ nW2,
                                               const float* __restrict__ nb2,
                                               const float* __restrict__ zpre,
                                               float* __restrict__ out0) {
  __shared__ float w1[64 * 64];
  __shared__ float w2[64 * 64];
  __shared__ float ns[64 * 64];
  __shared__ float h2[64 * 64];
  __shared__ float gb[64];
  const int tid = threadIdx.x;
  const long n0 = (long)blockIdx.x * 64;
#pragma unroll
  for (int rep = 0; rep < 16; rep++) {
    int idx = rep * 256 + tid;
    w1[idx] = nW1[idx];             // rows 0..63 (nodes part)
    w2[idx] = nW2[idx];
    ns[idx] = nodes[n0 * 64 + idx];
  }
  if (tid < 64) {
    float s = nb1[tid];
#pragma unroll
    for (int j = 0; j < 8; j++) s += g[j] * nW1[(long)(8256 + j) * 64 + tid];
    gb[tid] = s;
  }
  __syncthreads();
#pragma unroll 2
  for (int rep = 0; rep < 16; rep++) {
    int idx = rep * 256 + tid;
    int i = idx >> 6, c = idx & 63;
    float z = gb[c] + zpre[(n0 + i) * 64 + c];
#pragma unroll 8
    for (int k = 0; k < 64; k++) z += ns[i * 64 + k] * w1[k * 64 + c];
    h2[idx] = fmaxf(z, 0.f);
  }
  __syncthreads();
#pragma unroll 2
  for (int rep = 0; rep < 16; rep++) {
    int idx = rep * 256 + tid;
    int i = idx >> 6, c = idx & 63;
    float z = nb2[c];
#pragma unroll 8
    for (int k = 0; k < 64; k++) z += h2[i * 64 + k] * w2[k * 64 + c];
    out0[(n0 + i) * 64 + c] = fmaxf(z, 0.f);
  }
}

extern "C" void kernel_launch(void* const* d_in, const int* in_sizes, int n_in,
                              void* d_out, int out_size, void* d_ws, size_t ws_size,
                              hipStream_t stream) {
  const float* nodes = (const float*)d_in[0];
  const float* edges = (const float*)d_in[1];
  const float* g = (const float*)d_in[2];
  const int* senders = (const int*)d_in[3];
  const int* receivers = (const int*)d_in[4];
  const float* eW1 = (const float*)d_in[5];
  const float* eb1 = (const float*)d_in[6];
  const float* eW2 = (const float*)d_in[7];
  const float* eb2 = (const float*)d_in[8];
  const float* nW1 = (const float*)d_in[9];
  const float* nb1 = (const float*)d_in[10];
  const float* nW2 = (const float*)d_in[11];
  const float* nb2 = (const float*)d_in[12];

  char* ws = (char*)d_ws;
  u16* eW1T = (u16*)(ws + 0);        // [4096][160] bf16, dies after G1
  float* accb = (float*)(ws + 0);    // [8192][64] f32, zeroed by k_mid (post-G1)
  u16* ein = (u16*)(ws + 2097152);   // [4096][160] bf16, dies after G1
  u16* nWmT = (u16*)(ws + 2097152);  // [128][4096] bf16, written by k_mid
  u16* eW2T = (u16*)(ws + 3407872);  // [4096][4096] bf16
  u16* h = (u16*)(ws + 36962304);    // [4096][4096] bf16 (ends 70.5MB)

  float* out_nodes = (float*)d_out;
  float* out_edges = (float*)d_out + 524288;

  dim3 b256(256);
  k_prep<<<2752, b256, 0, stream>>>(eW1, eW1T, edges, nodes, g, senders, receivers, ein);
  k_transpose<<<dim3(64, 64), b256, 0, stream>>>(eW2, eW2T, 4096, 4096, 4096);
  k_mgemm<0><<<dim3(32, 32), b256, 0, stream>>>(ein, eW1T, eb1, h, 4096, 4096, 160);
  k_mid<<<192, b256, 0, stream>>>(nW1, nWmT, accb);
  k_gemm256<<<dim3(256), dim3(512), 0, stream>>>(h, eW2T, eb2, out_edges, 4096, 4096);
  k_scatter_m<<<dim3(32, 8), b256, 0, stream>>>(out_edges, nWmT, senders, receivers, accb);
  k_final<<<128, b256, 0, stream>>>(nodes, g, nW1, nb1, nW2, nb2, accb, out_nodes);
}